// Round 4
// baseline (262.278 us; speedup 1.0000x reference)
//
#include <hip/hip_runtime.h>
#include <stdint.h>

#define B_ROWS 2048
#define C_CLS  9605
#define L_GRP  20
#define GM_BYTES (L_GRP * C_CLS) /* 192100 */
#define REPSTRIDE 9728           /* multiple of 4, > C_CLS */
#define LIST_OFF  39040          /* 64 + 4*REPSTRIDE rounded to 64 */
#define LIST_CAP  16384
#define NEG_BIG -3.0e38f

__device__ __forceinline__ float sigmoidf(float v) {
  return 1.0f / (1.0f + __expf(-v));
}

// our_rank_loss: d = x2-x1+0.05; s = sigmoid(10*d); d>0 ? 2*s : s
__device__ __forceinline__ float rank_loss(float x1, float x2) {
  float d = x2 - x1 + 0.05f;
  float s = 1.0f / (1.0f + __expf(-10.0f * d));
  return d > 0.0f ? 2.0f * s : s;
}

// order-preserving float<->uint mapping (unsigned atomicMax on floats)
__device__ __forceinline__ unsigned fmap(float f) {
  unsigned u = __float_as_uint(f);
  return (u & 0x80000000u) ? ~u : (u | 0x80000000u);
}
__device__ __forceinline__ float funmap(unsigned m) {
  unsigned u = (m & 0x80000000u) ? (m ^ 0x80000000u) : ~m;
  return __uint_as_float(u);
}

// sorted-insert into named registers t0..t10 (descending) — NO indexed array,
// so nothing can be demoted to scratch (round-3 VGPR_Count=24 smoking gun).
#define INS1(ti) { float hi = fmaxf(ti, a); a = fminf(ti, a); ti = hi; }
#define INSERT(v)                                                         \
  do {                                                                    \
    if ((v) > t10) {                                                      \
      float a = (v);                                                      \
      INS1(t0) INS1(t1) INS1(t2) INS1(t3) INS1(t4) INS1(t5) INS1(t6)      \
      INS1(t7) INS1(t8) INS1(t9) INS1(t10)                                \
    }                                                                     \
  } while (0)

// ws layout: [0]=flag int, [4]=list count int, [64..] 4 byte-shifted gid
// copies (copy m at 64 + m*REPSTRIDE + m), [LIST_OFF..] packed whitelist
// column list (c | l<<16). Single-block fused kernel: zero d_out + count,
// 0xFF-init gid region, vector-count nonzero bytes of group_mask's first
// L*C bytes (1000 -> byte/bool layout; 250 int32 / 500 fp32 -> 4B layout).
__global__ void probe_init_kernel(const uint4* __restrict__ gm,
                                  unsigned char* __restrict__ ws,
                                  float* __restrict__ out) {
  __shared__ int s_part[16];
  const int tid = threadIdx.x;  // 1024 threads
  if (tid == 0) {
    out[0] = 0.0f;
    ((int*)ws)[1] = 0;  // list count
  }
  for (int i = tid; i < 4 * REPSTRIDE; i += 1024) ws[64 + i] = 0xFF;
  int local = 0;
  const int nvec = GM_BYTES / 16;  // 12006 (tail = 4 bytes)
  for (int i = tid; i < nvec; i += 1024) {
    uint4 w = gm[i];
    unsigned a[4] = {w.x, w.y, w.z, w.w};
#pragma unroll
    for (int q = 0; q < 4; ++q) {
      local += ((a[q] & 0x000000FFu) != 0) + ((a[q] & 0x0000FF00u) != 0) +
               ((a[q] & 0x00FF0000u) != 0) + ((a[q] & 0xFF000000u) != 0);
    }
  }
  if (tid == 0) {
    const unsigned char* gb = (const unsigned char*)gm;
    for (int i = nvec * 16; i < GM_BYTES; ++i) local += (gb[i] != 0);
  }
#pragma unroll
  for (int off = 32; off; off >>= 1) local += __shfl_xor(local, off);
  if ((tid & 63) == 0) s_part[tid >> 6] = local;
  __syncthreads();
  if (tid == 0) {
    int tot = 0;
    for (int w = 0; w < 16; ++w) tot += s_part[w];
    ((int*)ws)[0] = tot;
  }
}

__global__ void build_gid_kernel(const void* gm, unsigned char* __restrict__ ws) {
  int i = blockIdx.x * blockDim.x + threadIdx.x;
  if (i >= GM_BYTES) return;
  const bool is_byte = (((const int*)ws)[0] > 600);
  bool m;
  if (is_byte) m = ((const unsigned char*)gm)[i] != 0;
  else         m = ((const unsigned int*)gm)[i] != 0u;
  if (m) {
    int l = i / C_CLS;
    int c = i - l * C_CLS;
    unsigned char* base = ws + 64;
#pragma unroll
    for (int r = 0; r < 4; ++r) base[r * REPSTRIDE + r + c] = (unsigned char)l;
    int slot = atomicAdd(&((int*)ws)[1], 1);
    if (slot < LIST_CAP) ((int*)(ws + LIST_OFF))[slot] = c | (l << 16);
  }
}

__global__ __launch_bounds__(256, 4) void loss_kernel(
    const float* __restrict__ x, const int* __restrict__ y,
    const int* __restrict__ yn, const unsigned char* __restrict__ ws,
    float* __restrict__ out) {
  __shared__ unsigned s_gmax[L_GRP];
  __shared__ unsigned s_act, s_actn;
  __shared__ float s_wtop[4 * 11];
  const int tid = threadIdx.x;
  const int lane = tid & 63;
  const int wave = tid >> 6;
  const int row = blockIdx.x;  // grid = B_ROWS

  const size_t base = (size_t)row * C_CLS;
  const int mis = (int)(base & 3);
  const int peel = (4 - mis) & 3;
  const float* xr = x + base;
  const int* yr = y + base;
  const int* nr = yn + base;
  const unsigned char* gidc = ws + 64 + mis * REPSTRIDE + mis;  // gidc[c]=gid[c]

  if (tid < L_GRP) s_gmax[tid] = 0u;  // 0 < fmap(any real float)
  if (tid == 0) { s_act = 0u; s_actn = 0u; }
  __syncthreads();

  float t0 = NEG_BIG, t1 = NEG_BIG, t2 = NEG_BIG, t3 = NEG_BIG, t4 = NEG_BIG,
        t5 = NEG_BIG, t6 = NEG_BIG, t7 = NEG_BIG, t8 = NEG_BIG, t9 = NEG_BIG,
        t10 = NEG_BIG;

  // head peel to reach 16B alignment (<=3 scalar elements)
  if (tid < peel) {
    float v = xr[tid];
    INSERT(v);
    unsigned gk = gidc[tid];
    if (gk < L_GRP) atomicMax(&s_gmax[gk], fmap(v));
  }

  const int nvec = (C_CLS - peel) >> 2;
  const float4* x4 = (const float4*)(xr + peel);
  const unsigned* g4 = (const unsigned*)(gidc + peel);

  // main loop: ONLY x (16B) + gid word (4B, L1/L2-hot); explicit prefetch
  int j = tid;
  bool valid = j < nvec;
  float4 xv = {0.f, 0.f, 0.f, 0.f};
  unsigned gw = 0xFFFFFFFFu;
  if (valid) { xv = x4[j]; gw = g4[j]; }
  while (valid) {
    const int jn = j + 256;
    const bool vn = jn < nvec;
    float4 xn = {0.f, 0.f, 0.f, 0.f};
    unsigned gn = 0xFFFFFFFFu;
    if (vn) { xn = x4[jn]; gn = g4[jn]; }

    const float m4 = fmaxf(fmaxf(xv.x, xv.y), fmaxf(xv.z, xv.w));
    if (m4 > t10) {
      INSERT(xv.x); INSERT(xv.y); INSERT(xv.z); INSERT(xv.w);
    }
    if (gw != 0xFFFFFFFFu) {
      const unsigned g0 = gw & 0xFFu, g1 = (gw >> 8) & 0xFFu;
      const unsigned g2 = (gw >> 16) & 0xFFu, g3 = gw >> 24;
      if (g0 < L_GRP) atomicMax(&s_gmax[g0], fmap(xv.x));
      if (g1 < L_GRP) atomicMax(&s_gmax[g1], fmap(xv.y));
      if (g2 < L_GRP) atomicMax(&s_gmax[g2], fmap(xv.z));
      if (g3 < L_GRP) atomicMax(&s_gmax[g3], fmap(xv.w));
    }
    xv = xn; gw = gn; j = jn; valid = vn;
  }

  // tail (<=3 scalar elements)
  const int tail0 = peel + (nvec << 2);
  if (tid < C_CLS - tail0) {
    const int c = tail0 + tid;
    float v = xr[c];
    INSERT(v);
    unsigned gk = gidc[c];
    if (gk < L_GRP) atomicMax(&s_gmax[gk], fmap(v));
  }

  // phase B: y / y_neg only at whitelist columns (same list for all rows,
  // L2-broadcast). ~1000 entries -> 4 iters/thread of 2 scalar gathers.
  {
    const int cnt = ((const int*)ws)[1];
    const int* list = (const int*)(ws + LIST_OFF);
    const int n = cnt < LIST_CAP ? cnt : LIST_CAP;
    unsigned aL = 0u, anL = 0u;
    for (int i = tid; i < n; i += 256) {
      const int e = list[i];
      const int c = e & 0xFFFF;
      const unsigned bit = 1u << (e >> 16);
      if (yr[c] != 0) aL |= bit;
      if (nr[c] != 0) anL |= bit;
    }
    if (aL) atomicOr(&s_act, aL);    // ~1 positive/row -> almost always 0
    if (anL) atomicOr(&s_actn, anL);
  }

  // wave top-11: 11 rounds of max-extract from 64 sorted per-lane lists
  float cur = t0;
  float mr[11];
#pragma unroll
  for (int r = 0; r < 11; ++r) {
    float m = cur;
#pragma unroll
    for (int off = 32; off; off >>= 1) m = fmaxf(m, __shfl_xor(m, off));
    mr[r] = m;
    if (r < 10) {
      unsigned long long b = __ballot(cur == m);
      int leader = (int)(__ffsll(b) - 1);
      if (lane == leader) {  // pop head (named registers, no scratch)
        t0 = t1; t1 = t2; t2 = t3; t3 = t4; t4 = t5; t5 = t6; t6 = t7;
        t7 = t8; t8 = t9; t9 = t10; t10 = NEG_BIG;
        cur = t0;
      }
    }
  }
  if (lane == 0) {
#pragma unroll
    for (int r = 0; r < 11; ++r) s_wtop[wave * 11 + r] = mr[r];
  }
  __syncthreads();  // publishes s_wtop / s_gmax / s_act / s_actn

  if (wave == 0) {
    // merge 4 waves' sorted top-11 (44 candidates): 11 extract rounds
    float v = (lane < 44) ? s_wtop[lane] : NEG_BIG;
    float eleventh = NEG_BIG;
#pragma unroll
    for (int r = 0; r < 11; ++r) {
      float m = v;
#pragma unroll
      for (int off = 32; off; off >>= 1) m = fmaxf(m, __shfl_xor(m, off));
      eleventh = m;
      if (r < 10) {
        unsigned long long b = __ballot(v == m);
        int leader = (int)(__ffsll(b) - 1);
        if (lane == leader) v = NEG_BIG;
      }
    }

    const unsigned aL = s_act, anL = s_actn;
    const bool has_gt = (aL != 0u);
    const int g = has_gt ? (__ffs(aL) - 1) : 0;  // argmax of bool = first
    const float thres = fmaxf(sigmoidf(eleventh), 0.5f);

    float union_max = NEG_BIG, gt_sg = 0.0f, inc_max = NEG_BIG, inc_neg = 0.0f;
#pragma unroll
    for (int l = 0; l < L_GRP; ++l) {
      float sg = sigmoidf(funmap(s_gmax[l]));
      union_max = fmaxf(union_max, sg);
      if (l == g) gt_sg = sg; else inc_max = fmaxf(inc_max, sg);
      if ((anL >> l) & 1u) inc_neg = fmaxf(inc_neg, sg);
    }
    inc_max = fmaxf(inc_max, 0.0f);
    inc_neg = fmaxf(inc_neg, 0.0f);

    float loss;
    if (has_gt) {
      loss = rank_loss(gt_sg, thres);
      if (inc_max > 0.0f) loss += 0.5f * rank_loss(thres, inc_max);
      loss += 0.5f * rank_loss(thres, (inc_neg > 0.0f) ? inc_neg : inc_max);
    } else {
      loss = 0.5f * rank_loss(thres, union_max) + 0.5f * rank_loss(thres, inc_neg);
    }
    if (lane == 0) atomicAdd(out, loss);
  }
}

extern "C" void kernel_launch(void* const* d_in, const int* in_sizes, int n_in,
                              void* d_out, int out_size, void* d_ws, size_t ws_size,
                              hipStream_t stream) {
  (void)in_sizes; (void)n_in; (void)out_size; (void)ws_size;
  const float* x = (const float*)d_in[0];
  const int* y = (const int*)d_in[1];
  const int* yn = (const int*)d_in[2];
  const void* gm = d_in[3];

  unsigned char* ws = (unsigned char*)d_ws;

  probe_init_kernel<<<1, 1024, 0, stream>>>((const uint4*)gm, ws, (float*)d_out);
  build_gid_kernel<<<(GM_BYTES + 255) / 256, 256, 0, stream>>>(gm, ws);
  loss_kernel<<<B_ROWS, 256, 0, stream>>>(x, y, yn, ws, (float*)d_out);
}

// Round 5
// 257.627 us; speedup vs baseline: 1.0181x; 1.0181x over previous
//
#include <hip/hip_runtime.h>
#include <stdint.h>

#define B_ROWS 2048
#define C_CLS  9605
#define L_GRP  20
#define GM_BYTES (L_GRP * C_CLS) /* 192100 */
#define REPSTRIDE 9728           /* multiple of 4, > C_CLS */
#define LIST_OFF  39040          /* 64 + 4*REPSTRIDE rounded to 64 */
#define LIST_CAP  16384
#define NEG_BIG -3.0e38f

__device__ __forceinline__ float sigmoidf(float v) {
  return 1.0f / (1.0f + __expf(-v));
}

// our_rank_loss: d = x2-x1+0.05; s = sigmoid(10*d); d>0 ? 2*s : s
__device__ __forceinline__ float rank_loss(float x1, float x2) {
  float d = x2 - x1 + 0.05f;
  float s = 1.0f / (1.0f + __expf(-10.0f * d));
  return d > 0.0f ? 2.0f * s : s;
}

// order-preserving float<->uint mapping (unsigned atomicMax on floats)
__device__ __forceinline__ unsigned fmap(float f) {
  unsigned u = __float_as_uint(f);
  return (u & 0x80000000u) ? ~u : (u | 0x80000000u);
}
__device__ __forceinline__ float funmap(unsigned m) {
  unsigned u = (m & 0x80000000u) ? (m ^ 0x80000000u) : ~m;
  return __uint_as_float(u);
}

// sorted-insert into named registers t0..t10 (descending) — NO indexed array,
// so nothing can be demoted to scratch.
#define INS1(ti) { float hi = fmaxf(ti, a); a = fminf(ti, a); ti = hi; }
#define INSERT(v)                                                         \
  do {                                                                    \
    if ((v) > t10) {                                                      \
      float a = (v);                                                      \
      INS1(t0) INS1(t1) INS1(t2) INS1(t3) INS1(t4) INS1(t5) INS1(t6)      \
      INS1(t7) INS1(t8) INS1(t9) INS1(t10)                                \
    }                                                                     \
  } while (0)

#define PROC(av, wv)                                                          \
  do {                                                                        \
    const float m4_ = fmaxf(fmaxf(av.x, av.y), fmaxf(av.z, av.w));            \
    if (m4_ > t10) { INSERT(av.x); INSERT(av.y); INSERT(av.z); INSERT(av.w); }\
    if ((wv) != 0xFFFFFFFFu) {                                                \
      const unsigned q0_ = (wv) & 0xFFu, q1_ = ((wv) >> 8) & 0xFFu,           \
                     q2_ = ((wv) >> 16) & 0xFFu, q3_ = (wv) >> 24;            \
      if (q0_ < L_GRP) atomicMax(&s_gmax[q0_], fmap(av.x));                   \
      if (q1_ < L_GRP) atomicMax(&s_gmax[q1_], fmap(av.y));                   \
      if (q2_ < L_GRP) atomicMax(&s_gmax[q2_], fmap(av.z));                   \
      if (q3_ < L_GRP) atomicMax(&s_gmax[q3_], fmap(av.w));                   \
    }                                                                         \
  } while (0)

// ws layout: [0]=flag int, [4]=list count int, [64..] 4 byte-shifted gid
// copies (copy m at 64 + m*REPSTRIDE + m), [LIST_OFF..] packed whitelist
// column list (c | l<<16). Single-block fused kernel: zero d_out + count,
// 0xFF-init gid region, vector-count nonzero bytes of group_mask's first
// L*C bytes (1000 -> byte/bool layout; 250 int32 / 500 fp32 -> 4B layout).
__global__ void probe_init_kernel(const uint4* __restrict__ gm,
                                  unsigned char* __restrict__ ws,
                                  float* __restrict__ out) {
  __shared__ int s_part[16];
  const int tid = threadIdx.x;  // 1024 threads
  if (tid == 0) {
    out[0] = 0.0f;
    ((int*)ws)[1] = 0;  // list count
  }
  for (int i = tid; i < 4 * REPSTRIDE; i += 1024) ws[64 + i] = 0xFF;
  int local = 0;
  const int nvec = GM_BYTES / 16;  // 12006 (tail = 4 bytes)
  for (int i = tid; i < nvec; i += 1024) {
    uint4 w = gm[i];
    unsigned a[4] = {w.x, w.y, w.z, w.w};
#pragma unroll
    for (int q = 0; q < 4; ++q) {
      local += ((a[q] & 0x000000FFu) != 0) + ((a[q] & 0x0000FF00u) != 0) +
               ((a[q] & 0x00FF0000u) != 0) + ((a[q] & 0xFF000000u) != 0);
    }
  }
  if (tid == 0) {
    const unsigned char* gb = (const unsigned char*)gm;
    for (int i = nvec * 16; i < GM_BYTES; ++i) local += (gb[i] != 0);
  }
#pragma unroll
  for (int off = 32; off; off >>= 1) local += __shfl_xor(local, off);
  if ((tid & 63) == 0) s_part[tid >> 6] = local;
  __syncthreads();
  if (tid == 0) {
    int tot = 0;
    for (int w = 0; w < 16; ++w) tot += s_part[w];
    ((int*)ws)[0] = tot;
  }
}

__global__ void build_gid_kernel(const void* gm, unsigned char* __restrict__ ws) {
  int i = blockIdx.x * blockDim.x + threadIdx.x;
  if (i >= GM_BYTES) return;
  const bool is_byte = (((const int*)ws)[0] > 600);
  bool m;
  if (is_byte) m = ((const unsigned char*)gm)[i] != 0;
  else         m = ((const unsigned int*)gm)[i] != 0u;
  if (m) {
    int l = i / C_CLS;
    int c = i - l * C_CLS;
    unsigned char* base = ws + 64;
#pragma unroll
    for (int r = 0; r < 4; ++r) base[r * REPSTRIDE + r + c] = (unsigned char)l;
    int slot = atomicAdd(&((int*)ws)[1], 1);
    if (slot < LIST_CAP) ((int*)(ws + LIST_OFF))[slot] = c | (l << 16);
  }
}

__global__ __launch_bounds__(256, 8) void loss_kernel(
    const float* __restrict__ x, const int* __restrict__ y,
    const int* __restrict__ yn, const unsigned char* __restrict__ ws,
    float* __restrict__ out) {
  __shared__ unsigned s_gmax[L_GRP];
  __shared__ unsigned s_act, s_actn;
  __shared__ float s_wtop[4 * 11];
  const int tid = threadIdx.x;
  const int lane = tid & 63;
  const int wave = tid >> 6;
  const int row = blockIdx.x;  // grid = B_ROWS

  const size_t base = (size_t)row * C_CLS;
  const int mis = (int)(base & 3);
  const int peel = (4 - mis) & 3;
  const float* xr = x + base;
  const int* yr = y + base;
  const int* nr = yn + base;
  const unsigned char* gidc = ws + 64 + mis * REPSTRIDE + mis;  // gidc[c]=gid[c]

  if (tid < L_GRP) s_gmax[tid] = 0u;  // 0 < fmap(any real float)
  if (tid == 0) { s_act = 0u; s_actn = 0u; }
  __syncthreads();

  float t0 = NEG_BIG, t1 = NEG_BIG, t2 = NEG_BIG, t3 = NEG_BIG, t4 = NEG_BIG,
        t5 = NEG_BIG, t6 = NEG_BIG, t7 = NEG_BIG, t8 = NEG_BIG, t9 = NEG_BIG,
        t10 = NEG_BIG;

  // head peel to reach 16B alignment (<=3 scalar elements)
  if (tid < peel) {
    float v = xr[tid];
    INSERT(v);
    unsigned gk = gidc[tid];
    if (gk < L_GRP) atomicMax(&s_gmax[gk], fmap(v));
  }

  const int nvec = (C_CLS - peel) >> 2;
  const float4* x4 = (const float4*)(xr + peel);
  const unsigned* g4 = (const unsigned*)(gidc + peel);

  // main loop: 4 INDEPENDENT float4+gid loads per round (80 B/lane in flight)
  // round-4 post-mortem: depth-1 prefetch left the kernel latency-bound at
  // 29% VALU / 21% HBM — MLP, not BW, was the constraint.
  for (int jb = tid; jb < nvec; jb += 1024) {
    const int j1 = jb + 256, j2 = jb + 512, j3 = jb + 768;
    const bool k1 = j1 < nvec, k2 = j2 < nvec, k3 = j3 < nvec;
    float4 a0 = x4[jb];
    float4 a1 = x4[k1 ? j1 : jb];
    float4 a2 = x4[k2 ? j2 : jb];
    float4 a3 = x4[k3 ? j3 : jb];
    unsigned w0 = g4[jb];
    unsigned w1 = k1 ? g4[j1] : 0xFFFFFFFFu;
    unsigned w2 = k2 ? g4[j2] : 0xFFFFFFFFu;
    unsigned w3 = k3 ? g4[j3] : 0xFFFFFFFFu;
    if (!k1) a1.x = a1.y = a1.z = a1.w = NEG_BIG;
    if (!k2) a2.x = a2.y = a2.z = a2.w = NEG_BIG;
    if (!k3) a3.x = a3.y = a3.z = a3.w = NEG_BIG;
    PROC(a0, w0);
    PROC(a1, w1);
    PROC(a2, w2);
    PROC(a3, w3);
  }

  // tail (<=3 scalar elements)
  const int tail0 = peel + (nvec << 2);
  if (tid < C_CLS - tail0) {
    const int c = tail0 + tid;
    float v = xr[c];
    INSERT(v);
    unsigned gk = gidc[c];
    if (gk < L_GRP) atomicMax(&s_gmax[gk], fmap(v));
  }

  // phase B: y / y_neg only at whitelist columns (same list for all rows).
  // ~1000 entries -> 4 clamped-index entries/thread, 8 independent gathers.
  {
    const int cntr = ((const int*)ws)[1];
    const int n = cntr < LIST_CAP ? cntr : LIST_CAP;
    const int* list = (const int*)(ws + LIST_OFF);
    unsigned aL = 0u, anL = 0u;
#pragma unroll
    for (int k = 0; k < 4; ++k) {
      const int i = tid + k * 256;
      const bool ok = i < n;
      const int e = list[ok ? i : 0];
      const int c = e & 0xFFFF;
      const unsigned bit = ok ? (1u << (e >> 16)) : 0u;
      if (yr[c] != 0) aL |= bit;
      if (nr[c] != 0) anL |= bit;
    }
    for (int i = tid + 1024; i < n; i += 256) {  // safety (normally empty)
      const int e = list[i];
      const int c = e & 0xFFFF;
      const unsigned bit = 1u << (e >> 16);
      if (yr[c] != 0) aL |= bit;
      if (nr[c] != 0) anL |= bit;
    }
    if (aL) atomicOr(&s_act, aL);
    if (anL) atomicOr(&s_actn, anL);
  }

  // wave top-11: 11 rounds of max-extract from 64 sorted per-lane lists
  float cur = t0;
  float mr[11];
#pragma unroll
  for (int r = 0; r < 11; ++r) {
    float m = cur;
#pragma unroll
    for (int off = 32; off; off >>= 1) m = fmaxf(m, __shfl_xor(m, off));
    mr[r] = m;
    if (r < 10) {
      unsigned long long b = __ballot(cur == m);
      int leader = (int)(__ffsll(b) - 1);
      if (lane == leader) {  // pop head (named registers, no scratch)
        t0 = t1; t1 = t2; t2 = t3; t3 = t4; t4 = t5; t5 = t6; t6 = t7;
        t7 = t8; t8 = t9; t9 = t10; t10 = NEG_BIG;
        cur = t0;
      }
    }
  }
  if (lane == 0) {
#pragma unroll
    for (int r = 0; r < 11; ++r) s_wtop[wave * 11 + r] = mr[r];
  }
  __syncthreads();  // publishes s_wtop / s_gmax / s_act / s_actn

  if (wave == 0) {
    // merge 4 waves' sorted top-11 (44 candidates): 11 extract rounds
    float v = (lane < 44) ? s_wtop[lane] : NEG_BIG;
    float eleventh = NEG_BIG;
#pragma unroll
    for (int r = 0; r < 11; ++r) {
      float m = v;
#pragma unroll
      for (int off = 32; off; off >>= 1) m = fmaxf(m, __shfl_xor(m, off));
      eleventh = m;
      if (r < 10) {
        unsigned long long b = __ballot(v == m);
        int leader = (int)(__ffsll(b) - 1);
        if (lane == leader) v = NEG_BIG;
      }
    }

    const unsigned aL = s_act, anL = s_actn;
    const bool has_gt = (aL != 0u);
    const int g = has_gt ? (__ffs(aL) - 1) : 0;  // argmax of bool = first
    const float thres = fmaxf(sigmoidf(eleventh), 0.5f);

    float union_max = NEG_BIG, gt_sg = 0.0f, inc_max = NEG_BIG, inc_neg = 0.0f;
#pragma unroll
    for (int l = 0; l < L_GRP; ++l) {
      float sg = sigmoidf(funmap(s_gmax[l]));
      union_max = fmaxf(union_max, sg);
      if (l == g) gt_sg = sg; else inc_max = fmaxf(inc_max, sg);
      if ((anL >> l) & 1u) inc_neg = fmaxf(inc_neg, sg);
    }
    inc_max = fmaxf(inc_max, 0.0f);
    inc_neg = fmaxf(inc_neg, 0.0f);

    float loss;
    if (has_gt) {
      loss = rank_loss(gt_sg, thres);
      if (inc_max > 0.0f) loss += 0.5f * rank_loss(thres, inc_max);
      loss += 0.5f * rank_loss(thres, (inc_neg > 0.0f) ? inc_neg : inc_max);
    } else {
      loss = 0.5f * rank_loss(thres, union_max) + 0.5f * rank_loss(thres, inc_neg);
    }
    if (lane == 0) atomicAdd(out, loss);
  }
}

extern "C" void kernel_launch(void* const* d_in, const int* in_sizes, int n_in,
                              void* d_out, int out_size, void* d_ws, size_t ws_size,
                              hipStream_t stream) {
  (void)in_sizes; (void)n_in; (void)out_size; (void)ws_size;
  const float* x = (const float*)d_in[0];
  const int* y = (const int*)d_in[1];
  const int* yn = (const int*)d_in[2];
  const void* gm = d_in[3];

  unsigned char* ws = (unsigned char*)d_ws;

  probe_init_kernel<<<1, 1024, 0, stream>>>((const uint4*)gm, ws, (float*)d_out);
  build_gid_kernel<<<(GM_BYTES + 255) / 256, 256, 0, stream>>>(gm, ws);
  loss_kernel<<<B_ROWS, 256, 0, stream>>>(x, y, yn, ws, (float*)d_out);
}